// Round 8
// baseline (48.334 us; speedup 1.0000x reference)
//
#include <hip/hip_runtime.h>
#include <math.h>

// OFDM: per-row 64-pt complex FFT (radix-2 DIF, lane-per-bin).
// Stages 0-1: scalar, permlane32/16_swap. Stages 2-5: row-PAIR packed f32x2
// via compiler packed math (v_pk_fma_f32). Stage-4 twiddle is +/-i -> selects.
// Epilogue: scalar per row, fmaf with readlane SGPR operands directly (no
// SGPR->VGPR mov bloat). Single-pass launch: each wave owns one 8-row block.
// Epilogue in bit-reversed domain; scatter-store restores natural order.

typedef float f32x2 __attribute__((ext_vector_type(2)));
typedef unsigned int uint2v __attribute__((ext_vector_type(2)));

struct LaneConst {
    float twc0, tws0, twc1, tws1, sgn0, sgn1;  // scalar stages 0,1
    f32x2 psgn[4];            // stages 2..5 butterfly sign (broadcast pair)
    f32x2 C[2], S[2], Sn[2];  // stages 2,3 twiddle (stage 4 = +/-i, stage 5 = 1)
    bool  rot4;               // stage-4: this lane multiplies by -i
    float w0, w1, w2, w3;     // pilot interp weights (scalar)
    int   kk;                 // natural bin index = brev6(lane)
};

__device__ __forceinline__ f32x2 pk_fma(f32x2 a, f32x2 b, f32x2 cc) {
#if __has_builtin(__builtin_elementwise_fma)
    return __builtin_elementwise_fma(a, b, cc);
#else
    return a * b + cc;
#endif
}

template <int CTRL>
__device__ __forceinline__ float dpp_mov(float x) {
    return __int_as_float(__builtin_amdgcn_update_dpp(
        0, __float_as_int(x), CTRL, 0xF, 0xF, true));
}
__device__ __forceinline__ float swz4(float x) {
    return __int_as_float(__builtin_amdgcn_ds_swizzle(__float_as_int(x), 0x101F));
}
__device__ __forceinline__ float rdlane(float x, int l) {
    return __int_as_float(__builtin_amdgcn_readlane(__float_as_int(x), l));
}

// scalar stage 0 (xor32) + stage 1 (xor16) — proven R2/R4/R6
__device__ __forceinline__ void stage01(float& xr, float& xi, const LaneConst& c) {
    float ar, ai, t;
    {
        uint2v tr = __builtin_amdgcn_permlane32_swap(
            (unsigned)__float_as_int(xr), (unsigned)__float_as_int(xr), false, false);
        uint2v ti = __builtin_amdgcn_permlane32_swap(
            (unsigned)__float_as_int(xi), (unsigned)__float_as_int(xi), false, false);
        ar = fmaf(c.sgn0, __int_as_float((int)tr[1]), __int_as_float((int)tr[0]));
        ai = fmaf(c.sgn0, __int_as_float((int)ti[1]), __int_as_float((int)ti[0]));
    }
    t  = fmaf(ar, c.twc0, -(ai * c.tws0));
    xi = fmaf(ar, c.tws0, ai * c.twc0);
    xr = t;
    {
        uint2v tr = __builtin_amdgcn_permlane16_swap(
            (unsigned)__float_as_int(xr), (unsigned)__float_as_int(xr), false, false);
        uint2v ti = __builtin_amdgcn_permlane16_swap(
            (unsigned)__float_as_int(xi), (unsigned)__float_as_int(xi), false, false);
        ar = fmaf(c.sgn1, __int_as_float((int)tr[1]), __int_as_float((int)tr[0]));
        ai = fmaf(c.sgn1, __int_as_float((int)ti[1]), __int_as_float((int)ti[0]));
    }
    t  = fmaf(ar, c.twc1, -(ai * c.tws1));
    xi = fmaf(ar, c.tws1, ai * c.twc1);
    xr = t;
}

// packed stages 2..5 for a row pair (rows in .x/.y); proven R6 except stage-4
// twiddle which is +/-i: for rot4 lanes (z) -> (zi, -zr).
__device__ __forceinline__ void fft_tail_pair(f32x2& zr, f32x2& zi, const LaneConst& c) {
    f32x2 pr, pi, ar, ai;
    // ---- stage 2: xor8 via DPP row_ror:8 ----
    pr.x = dpp_mov<0x128>(zr.x); pr.y = dpp_mov<0x128>(zr.y);
    pi.x = dpp_mov<0x128>(zi.x); pi.y = dpp_mov<0x128>(zi.y);
    ar = pk_fma(c.psgn[0], zr, pr);
    ai = pk_fma(c.psgn[0], zi, pi);
    zr = pk_fma(ar, c.C[0], ai * c.Sn[0]);
    zi = pk_fma(ai, c.C[0], ar * c.S[0]);
    // ---- stage 3: xor4 via ds_swizzle ----
    pr.x = swz4(zr.x); pr.y = swz4(zr.y);
    pi.x = swz4(zi.x); pi.y = swz4(zi.y);
    ar = pk_fma(c.psgn[1], zr, pr);
    ai = pk_fma(c.psgn[1], zi, pi);
    zr = pk_fma(ar, c.C[1], ai * c.Sn[1]);
    zi = pk_fma(ai, c.C[1], ar * c.S[1]);
    // ---- stage 4: xor2 via DPP quad_perm [2,3,0,1]; twiddle is 1 or -i ----
    pr.x = dpp_mov<0x4E>(zr.x); pr.y = dpp_mov<0x4E>(zr.y);
    pi.x = dpp_mov<0x4E>(zi.x); pi.y = dpp_mov<0x4E>(zi.y);
    ar = pk_fma(c.psgn[2], zr, pr);
    ai = pk_fma(c.psgn[2], zi, pi);
    zr = c.rot4 ? ai : ar;          // (ar + i*ai) * (-i) = ai - i*ar
    zi = c.rot4 ? -ar : ai;
    // ---- stage 5: xor1 via DPP quad_perm [1,0,3,2]; twiddle == 1 ----
    pr.x = dpp_mov<0xB1>(zr.x); pr.y = dpp_mov<0xB1>(zr.y);
    pi.x = dpp_mov<0xB1>(zi.x); pi.y = dpp_mov<0xB1>(zi.y);
    zr = pk_fma(c.psgn[3], zr, pr);
    zi = pk_fma(c.psgn[3], zi, pi);
}

// scalar epilogue per row (R4 form: fmaf reads readlane SGPRs directly)
__device__ __forceinline__ void epilogue_row(float fr, float fi,
                                             float* __restrict__ po,
                                             const LaneConst& c) {
    const float h0r = rdlane(fr, 52), h0i = rdlane(fi, 52);
    const float h1r = rdlane(fr, 38), h1i = rdlane(fi, 38);
    const float h2r = rdlane(fr, 57), h2i = rdlane(fi, 57);
    const float h3r = rdlane(fr, 43), h3i = rdlane(fi, 43);
    float hr = c.w0 * h0r;
    hr = fmaf(c.w1, h1r, hr);
    hr = fmaf(c.w2, h2r, hr);
    hr = fmaf(c.w3, h3r, hr);
    float hi = c.w0 * h0i;
    hi = fmaf(c.w1, h1i, hi);
    hi = fmaf(c.w2, h2i, hi);
    hi = fmaf(c.w3, h3i, hi);
    const float denom = fmaf(hr, hr, fmaf(hi, hi, 1e-8f));
    const float rd = __builtin_amdgcn_rcpf(denom);
    const float eqr = fmaf(fr, hr,  fi * hi) * rd;
    const float eqi = fmaf(fi, hr, -(fr * hi)) * rd;
    __builtin_nontemporal_store(eqr, po + c.kk);
    __builtin_nontemporal_store(eqi, po + 64 + c.kk);
}

__device__ __forceinline__ void do_rows8(const float* __restrict__ x,
                                         float* __restrict__ out,
                                         int r0, int lane, const LaneConst& c) {
    float xr[8], xi[8];
    #pragma unroll
    for (int j = 0; j < 8; ++j) {
        const float* px = x + (size_t)(r0 + j) * 128;
        xr[j] = px[lane];
        xi[j] = px[64 + lane];
    }
    #pragma unroll
    for (int j = 0; j < 8; ++j)
        stage01(xr[j], xi[j], c);
    float* po = out + (size_t)r0 * 128;
    #pragma unroll
    for (int p = 0; p < 4; ++p) {
        f32x2 zr = { xr[2 * p], xr[2 * p + 1] };
        f32x2 zi = { xi[2 * p], xi[2 * p + 1] };
        fft_tail_pair(zr, zi, c);
        epilogue_row(zr.x, zi.x, po + (size_t)(2 * p) * 128, c);
        epilogue_row(zr.y, zi.y, po + (size_t)(2 * p + 1) * 128, c);
    }
}

__global__ __launch_bounds__(256) void ofdm_kernel(const float* __restrict__ x,
                                                   float* __restrict__ out,
                                                   int nrows) {
    const int lane = threadIdx.x & 63;
    const int wid  = threadIdx.x >> 6;
    const int wavesPerBlock = blockDim.x >> 6;
    const int gw = blockIdx.x * wavesPerBlock + wid;
    const int gstride = gridDim.x * wavesPerBlock;

    LaneConst c;
    {
        const bool up0 = (lane & 32) != 0;
        const float th0 = (float)(lane & 31) * 0.0981747704246810387f; // pi/32
        c.twc0 = up0 ? cosf(th0) : 1.0f;
        c.tws0 = up0 ? -sinf(th0) : 0.0f;
        c.sgn0 = up0 ? -1.0f : 1.0f;
        const bool up1 = (lane & 16) != 0;
        const float th1 = (float)((lane & 15) << 1) * 0.0981747704246810387f;
        c.twc1 = up1 ? cosf(th1) : 1.0f;
        c.tws1 = up1 ? -sinf(th1) : 0.0f;
        c.sgn1 = up1 ? -1.0f : 1.0f;
        #pragma unroll
        for (int s = 2; s < 6; ++s) {
            const int half = 32 >> s;
            const bool up = (lane & half) != 0;
            const float sg = up ? -1.0f : 1.0f;
            c.psgn[s - 2] = (f32x2){sg, sg};
            if (s < 4) {
                const int t = (lane & (half - 1)) << s;
                const float th = (float)t * 0.0981747704246810387f;
                const float cc = up ? cosf(th) : 1.0f;
                const float ss = up ? -sinf(th) : 0.0f;  // W = e^{-i th}
                c.C[s - 2]  = (f32x2){cc, cc};
                c.S[s - 2]  = (f32x2){ss, ss};
                c.Sn[s - 2] = (f32x2){-ss, -ss};
            }
        }
        // stage 4: t = (lane&1)<<4 -> theta in {0, pi/2}; up lanes with t=16
        // multiply by e^{-i pi/2} = -i. Lower lanes or t=0: identity.
        c.rot4 = ((lane & 2) != 0) && ((lane & 1) != 0);
    }
    c.kk = (int)(__brev((unsigned)lane) >> 26);
    const int seg = (c.kk <= 25) ? 0 : (c.kk <= 39) ? 1 : 2; // pilots 11,25,39,53
    float a = (float)(c.kk - (11 + seg * 14)) * (1.0f / 14.0f);
    a = fminf(fmaxf(a, 0.0f), 1.0f);
    c.w0 = c.w1 = c.w2 = c.w3 = 0.0f;
    const float wa = 1.0f - a, wb = a;
    if (seg == 0) { c.w0 = wa; c.w1 = wb; }
    else if (seg == 1) { c.w1 = wa; c.w2 = wb; }
    else { c.w2 = wa; c.w3 = wb; }

    // single pass: each wave owns one 8-row block (grid sized to cover)
    for (int r = gw * 8; r + 8 <= nrows; r += gstride * 8)
        do_rows8(x, out, r, lane, c);

    // tail rows (unused when nrows % 8 == 0)
    const int tail = nrows & ~7;
    for (int rr = tail + gw; rr < nrows; rr += gstride) {
        const float* px = x + (size_t)rr * 128;
        float xr = px[lane], xi = px[64 + lane];
        stage01(xr, xi, c);
        f32x2 zr = { xr, xr }, zi = { xi, xi };
        fft_tail_pair(zr, zi, c);
        epilogue_row(zr.x, zi.x, out + (size_t)rr * 128, c);
    }
}

extern "C" void kernel_launch(void* const* d_in, const int* in_sizes, int n_in,
                              void* d_out, int out_size, void* d_ws, size_t ws_size,
                              hipStream_t stream) {
    const float* x = (const float*)d_in[0];
    float* out = (float*)d_out;
    const int nrows = in_sizes[0] / 128;     // 262144
    const int block = 256;                   // 4 waves/block
    const int wavesNeeded = (nrows + 7) / 8; // one 8-row block per wave
    const int grid = (wavesNeeded + 3) / 4;  // 8192 blocks -> single pass
    hipLaunchKernelGGL(ofdm_kernel, dim3(grid), dim3(block), 0, stream,
                       x, out, nrows);
}

// Round 9
// 47.455 us; speedup vs baseline: 1.0185x; 1.0185x over previous
//
#include <hip/hip_runtime.h>
#include <math.h>

// OFDM: per-row 64-pt complex FFT (radix-2 DIF, lane-per-bin).
// Stages 0-1: scalar, permlane32/16_swap. Stages 2-5: row-PAIR packed f32x2
// via compiler packed math (v_pk_fma_f32). Stage-4 twiddle = +/-i -> selects.
// Twiddle setup uses v_cos_f32/v_sin_f32 directly (input in REVOLUTIONS:
// angle t*pi/32 == t/64 rev) — no libm argument-reduction bloat (R7 lesson:
// 12 cosf/sinf libcalls ~300 insts/wave; hw ops ~25).
// Grid 2048: 32 rows/wave amortizes setup (R7 lesson #2).
// Epilogue packed (R6 form); bit-reversed domain; scatter-store restores order.

typedef float f32x2 __attribute__((ext_vector_type(2)));
typedef unsigned int uint2v __attribute__((ext_vector_type(2)));

struct LaneConst {
    float twc0, tws0, twc1, tws1, sgn0, sgn1;  // scalar stages 0,1
    f32x2 psgn[4];            // stages 2..5 butterfly sign (broadcast pair)
    f32x2 C[2], S[2], Sn[2];  // stages 2,3 twiddle (stage 4 = +/-i, stage 5 = 1)
    bool  rot4;               // stage-4: this lane multiplies by -i
    f32x2 pw0, pw1, pw2, pw3; // pilot interp weights (broadcast pair)
    int   kk;                 // natural bin index = brev6(lane)
};

__device__ __forceinline__ f32x2 pk_fma(f32x2 a, f32x2 b, f32x2 cc) {
#if __has_builtin(__builtin_elementwise_fma)
    return __builtin_elementwise_fma(a, b, cc);
#else
    return a * b + cc;
#endif
}

template <int CTRL>
__device__ __forceinline__ float dpp_mov(float x) {
    return __int_as_float(__builtin_amdgcn_update_dpp(
        0, __float_as_int(x), CTRL, 0xF, 0xF, true));
}
__device__ __forceinline__ float swz4(float x) {
    return __int_as_float(__builtin_amdgcn_ds_swizzle(__float_as_int(x), 0x101F));
}
__device__ __forceinline__ float rdlane(float x, int l) {
    return __int_as_float(__builtin_amdgcn_readlane(__float_as_int(x), l));
}

// scalar stage 0 (xor32) + stage 1 (xor16) — proven R2/R4/R6
__device__ __forceinline__ void stage01(float& xr, float& xi, const LaneConst& c) {
    float ar, ai, t;
    {
        uint2v tr = __builtin_amdgcn_permlane32_swap(
            (unsigned)__float_as_int(xr), (unsigned)__float_as_int(xr), false, false);
        uint2v ti = __builtin_amdgcn_permlane32_swap(
            (unsigned)__float_as_int(xi), (unsigned)__float_as_int(xi), false, false);
        ar = fmaf(c.sgn0, __int_as_float((int)tr[1]), __int_as_float((int)tr[0]));
        ai = fmaf(c.sgn0, __int_as_float((int)ti[1]), __int_as_float((int)ti[0]));
    }
    t  = fmaf(ar, c.twc0, -(ai * c.tws0));
    xi = fmaf(ar, c.tws0, ai * c.twc0);
    xr = t;
    {
        uint2v tr = __builtin_amdgcn_permlane16_swap(
            (unsigned)__float_as_int(xr), (unsigned)__float_as_int(xr), false, false);
        uint2v ti = __builtin_amdgcn_permlane16_swap(
            (unsigned)__float_as_int(xi), (unsigned)__float_as_int(xi), false, false);
        ar = fmaf(c.sgn1, __int_as_float((int)tr[1]), __int_as_float((int)tr[0]));
        ai = fmaf(c.sgn1, __int_as_float((int)ti[1]), __int_as_float((int)ti[0]));
    }
    t  = fmaf(ar, c.twc1, -(ai * c.tws1));
    xi = fmaf(ar, c.tws1, ai * c.twc1);
    xr = t;
}

// packed stages 2..5 for a row pair (rows in .x/.y) — R6 form + R7 stage-4 select
__device__ __forceinline__ void fft_tail_pair(f32x2& zr, f32x2& zi, const LaneConst& c) {
    f32x2 pr, pi, ar, ai;
    // ---- stage 2: xor8 via DPP row_ror:8 ----
    pr.x = dpp_mov<0x128>(zr.x); pr.y = dpp_mov<0x128>(zr.y);
    pi.x = dpp_mov<0x128>(zi.x); pi.y = dpp_mov<0x128>(zi.y);
    ar = pk_fma(c.psgn[0], zr, pr);
    ai = pk_fma(c.psgn[0], zi, pi);
    zr = pk_fma(ar, c.C[0], ai * c.Sn[0]);
    zi = pk_fma(ai, c.C[0], ar * c.S[0]);
    // ---- stage 3: xor4 via ds_swizzle ----
    pr.x = swz4(zr.x); pr.y = swz4(zr.y);
    pi.x = swz4(zi.x); pi.y = swz4(zi.y);
    ar = pk_fma(c.psgn[1], zr, pr);
    ai = pk_fma(c.psgn[1], zi, pi);
    zr = pk_fma(ar, c.C[1], ai * c.Sn[1]);
    zi = pk_fma(ai, c.C[1], ar * c.S[1]);
    // ---- stage 4: xor2 via DPP quad_perm [2,3,0,1]; twiddle is 1 or -i ----
    pr.x = dpp_mov<0x4E>(zr.x); pr.y = dpp_mov<0x4E>(zr.y);
    pi.x = dpp_mov<0x4E>(zi.x); pi.y = dpp_mov<0x4E>(zi.y);
    ar = pk_fma(c.psgn[2], zr, pr);
    ai = pk_fma(c.psgn[2], zi, pi);
    zr = c.rot4 ? ai : ar;          // (ar + i*ai) * (-i) = ai - i*ar
    zi = c.rot4 ? -ar : ai;
    // ---- stage 5: xor1 via DPP quad_perm [1,0,3,2]; twiddle == 1 ----
    pr.x = dpp_mov<0xB1>(zr.x); pr.y = dpp_mov<0xB1>(zr.y);
    pi.x = dpp_mov<0xB1>(zi.x); pi.y = dpp_mov<0xB1>(zi.y);
    zr = pk_fma(c.psgn[3], zr, pr);
    zi = pk_fma(c.psgn[3], zi, pi);
}

// packed epilogue for a row pair — R6 form (proven 46.8)
template <bool STORE_PAIR>
__device__ __forceinline__ void epilogue_pair(f32x2 zr, f32x2 zi,
                                              float* __restrict__ out,
                                              int r0, const LaneConst& c) {
    f32x2 p0r = { rdlane(zr.x, 52), rdlane(zr.y, 52) };
    f32x2 p0i = { rdlane(zi.x, 52), rdlane(zi.y, 52) };
    f32x2 p1r = { rdlane(zr.x, 38), rdlane(zr.y, 38) };
    f32x2 p1i = { rdlane(zi.x, 38), rdlane(zi.y, 38) };
    f32x2 p2r = { rdlane(zr.x, 57), rdlane(zr.y, 57) };
    f32x2 p2i = { rdlane(zi.x, 57), rdlane(zi.y, 57) };
    f32x2 p3r = { rdlane(zr.x, 43), rdlane(zr.y, 43) };
    f32x2 p3i = { rdlane(zi.x, 43), rdlane(zi.y, 43) };
    f32x2 hr = c.pw0 * p0r;
    hr = pk_fma(c.pw1, p1r, hr);
    hr = pk_fma(c.pw2, p2r, hr);
    hr = pk_fma(c.pw3, p3r, hr);
    f32x2 hi = c.pw0 * p0i;
    hi = pk_fma(c.pw1, p1i, hi);
    hi = pk_fma(c.pw2, p2i, hi);
    hi = pk_fma(c.pw3, p3i, hi);
    f32x2 den = pk_fma(hr, hr, pk_fma(hi, hi, (f32x2){1e-8f, 1e-8f}));
    f32x2 rd;
    rd.x = __builtin_amdgcn_rcpf(den.x);
    rd.y = __builtin_amdgcn_rcpf(den.y);
    f32x2 numr = pk_fma(zr, hr, zi * hi);
    f32x2 numi = pk_fma(zi, hr, zr * (-hi));
    f32x2 eqr = numr * rd;
    f32x2 eqi = numi * rd;
    float* po0 = out + (size_t)r0 * 128;
    __builtin_nontemporal_store(eqr.x, po0 + c.kk);
    __builtin_nontemporal_store(eqi.x, po0 + 64 + c.kk);
    if (STORE_PAIR) {
        float* po1 = po0 + 128;
        __builtin_nontemporal_store(eqr.y, po1 + c.kk);
        __builtin_nontemporal_store(eqi.y, po1 + 64 + c.kk);
    }
}

__device__ __forceinline__ void do_rows8(const float* __restrict__ x,
                                         float* __restrict__ out,
                                         int r0, int lane, const LaneConst& c) {
    float xr[8], xi[8];
    #pragma unroll
    for (int j = 0; j < 8; ++j) {
        const float* px = x + (size_t)(r0 + j) * 128;
        xr[j] = px[lane];
        xi[j] = px[64 + lane];
    }
    #pragma unroll
    for (int j = 0; j < 8; ++j)
        stage01(xr[j], xi[j], c);
    #pragma unroll
    for (int p = 0; p < 4; ++p) {
        f32x2 zr = { xr[2 * p], xr[2 * p + 1] };
        f32x2 zi = { xi[2 * p], xi[2 * p + 1] };
        fft_tail_pair(zr, zi, c);
        epilogue_pair<true>(zr, zi, out, r0 + 2 * p, c);
    }
}

__global__ __launch_bounds__(256) void ofdm_kernel(const float* __restrict__ x,
                                                   float* __restrict__ out,
                                                   int nrows) {
    const int lane = threadIdx.x & 63;
    const int wid  = threadIdx.x >> 6;
    const int wavesPerBlock = blockDim.x >> 6;
    const int gw = blockIdx.x * wavesPerBlock + wid;
    const int gstride = gridDim.x * wavesPerBlock;

    LaneConst c;
    {
        // v_cos_f32 / v_sin_f32 take REVOLUTIONS: angle t*(pi/32) == t/64 rev.
        const bool up0 = (lane & 32) != 0;
        const float f0 = (float)(lane & 31) * 0.015625f;   // t/64
        c.twc0 = up0 ? __builtin_amdgcn_cosf(f0) : 1.0f;
        c.tws0 = up0 ? -__builtin_amdgcn_sinf(f0) : 0.0f;
        c.sgn0 = up0 ? -1.0f : 1.0f;
        const bool up1 = (lane & 16) != 0;
        const float f1 = (float)((lane & 15) << 1) * 0.015625f;
        c.twc1 = up1 ? __builtin_amdgcn_cosf(f1) : 1.0f;
        c.tws1 = up1 ? -__builtin_amdgcn_sinf(f1) : 0.0f;
        c.sgn1 = up1 ? -1.0f : 1.0f;
        #pragma unroll
        for (int s = 2; s < 6; ++s) {
            const int half = 32 >> s;
            const bool up = (lane & half) != 0;
            const float sg = up ? -1.0f : 1.0f;
            c.psgn[s - 2] = (f32x2){sg, sg};
            if (s < 4) {
                const int t = (lane & (half - 1)) << s;
                const float fr = (float)t * 0.015625f;     // t/64 rev
                const float cc = up ? __builtin_amdgcn_cosf(fr) : 1.0f;
                const float ss = up ? -__builtin_amdgcn_sinf(fr) : 0.0f;
                c.C[s - 2]  = (f32x2){cc, cc};
                c.S[s - 2]  = (f32x2){ss, ss};
                c.Sn[s - 2] = (f32x2){-ss, -ss};
            }
        }
        // stage 4: t = (lane&1)<<4 -> theta in {0, pi/2}; lanes with up&&t=16
        // multiply by e^{-i pi/2} = -i.
        c.rot4 = ((lane & 2) != 0) && ((lane & 1) != 0);
    }
    c.kk = (int)(__brev((unsigned)lane) >> 26);
    const int seg = (c.kk <= 25) ? 0 : (c.kk <= 39) ? 1 : 2; // pilots 11,25,39,53
    float a = (float)(c.kk - (11 + seg * 14)) * (1.0f / 14.0f);
    a = fminf(fmaxf(a, 0.0f), 1.0f);
    float w0 = 0, w1 = 0, w2 = 0, w3 = 0;
    const float wa = 1.0f - a, wb = a;
    if (seg == 0) { w0 = wa; w1 = wb; }
    else if (seg == 1) { w1 = wa; w2 = wb; }
    else { w2 = wa; w3 = wb; }
    c.pw0 = (f32x2){w0, w0}; c.pw1 = (f32x2){w1, w1};
    c.pw2 = (f32x2){w2, w2}; c.pw3 = (f32x2){w3, w3};

    const int step = gstride * 8;
    int r = gw * 8;
    for (; r + 8 <= nrows; r += step)
        do_rows8(x, out, r, lane, c);

    // tail (unused for nrows % 8 == 0): strided row pairs, then odd row
    const int tail = nrows & ~7;
    for (int rr = tail + gw * 2; rr + 2 <= nrows; rr += gstride * 2) {
        const float* p0 = x + (size_t)rr * 128;
        float xr0 = p0[lane],        xi0 = p0[64 + lane];
        float xr1 = p0[128 + lane],  xi1 = p0[192 + lane];
        stage01(xr0, xi0, c);
        stage01(xr1, xi1, c);
        f32x2 zr = { xr0, xr1 }, zi = { xi0, xi1 };
        fft_tail_pair(zr, zi, c);
        epilogue_pair<true>(zr, zi, out, rr, c);
    }
    if ((nrows & 1) && gw == 0) {
        const int rr = nrows - 1;
        const float* p0 = x + (size_t)rr * 128;
        float xr0 = p0[lane], xi0 = p0[64 + lane];
        stage01(xr0, xi0, c);
        f32x2 zr = { xr0, xr0 }, zi = { xi0, xi0 };
        fft_tail_pair(zr, zi, c);
        epilogue_pair<false>(zr, zi, out, rr, c);
    }
}

extern "C" void kernel_launch(void* const* d_in, const int* in_sizes, int n_in,
                              void* d_out, int out_size, void* d_ws, size_t ws_size,
                              hipStream_t stream) {
    const float* x = (const float*)d_in[0];
    float* out = (float*)d_out;
    const int nrows = in_sizes[0] / 128;   // 262144
    const int block = 256;                 // 4 waves/block
    const int grid = 2048;                 // 8192 waves, 4 iters x 8 rows
    hipLaunchKernelGGL(ofdm_kernel, dim3(grid), dim3(block), 0, stream,
                       x, out, nrows);
}

// Round 10
// 46.414 us; speedup vs baseline: 1.0414x; 1.0224x over previous
//
#include <hip/hip_runtime.h>
#include <math.h>

// OFDM: per-row 64-pt complex FFT (radix-2 DIF, lane-per-bin), fully
// row-PAIR packed: ALL butterfly/twiddle math is v_pk_fma_f32/v_pk_mul_f32
// (compiler-generated; no inline asm -> no DPP hazard exposure).
// Cross-lane per 32-bit reg: xor32 -> permlane32_swap, xor16 ->
// permlane16_swap, xor8 -> DPP row_ror:8, xor4 -> ds_swizzle,
// xor2/xor1 -> DPP quad_perm. Stage-4 twiddle = +/-i -> selects.
// Twiddle setup: v_cos_f32/v_sin_f32 in REVOLUTIONS (t/64).
// Epilogue packed, in bit-reversed domain; scatter-store restores order.

typedef float f32x2 __attribute__((ext_vector_type(2)));
typedef unsigned int uint2v __attribute__((ext_vector_type(2)));

struct LaneConst {
    f32x2 psgn[6];            // stages 0..5 butterfly sign (broadcast pair)
    f32x2 C[4], S[4], Sn[4];  // stages 0..3 twiddle (S = -sin; stage4 = +/-i, stage5 = 1)
    bool  rot4;               // stage-4: this lane multiplies by -i
    f32x2 pw0, pw1, pw2, pw3; // pilot interp weights (broadcast pair)
    int   kk;                 // natural bin index = brev6(lane)
};

__device__ __forceinline__ f32x2 pk_fma(f32x2 a, f32x2 b, f32x2 cc) {
#if __has_builtin(__builtin_elementwise_fma)
    return __builtin_elementwise_fma(a, b, cc);
#else
    return a * b + cc;
#endif
}

template <int CTRL>
__device__ __forceinline__ float dpp_mov(float x) {
    return __int_as_float(__builtin_amdgcn_update_dpp(
        0, __float_as_int(x), CTRL, 0xF, 0xF, true));
}
__device__ __forceinline__ float swz4(float x) {
    return __int_as_float(__builtin_amdgcn_ds_swizzle(__float_as_int(x), 0x101F));
}
__device__ __forceinline__ float rdlane(float x, int l) {
    return __int_as_float(__builtin_amdgcn_readlane(__float_as_int(x), l));
}

// full packed FFT for a row pair (rows r0, r0+1 in .x/.y of zr, zi)
__device__ __forceinline__ void fft_pair(f32x2& zr, f32x2& zi, const LaneConst& c) {
    f32x2 lo, hi, ar, ai, pr, pi;
    // ---- stage 0: xor32 via permlane32_swap; bfly = sgn*hi + lo ----
    {
        uint2v t0 = __builtin_amdgcn_permlane32_swap(
            (unsigned)__float_as_int(zr.x), (unsigned)__float_as_int(zr.x), false, false);
        uint2v t1 = __builtin_amdgcn_permlane32_swap(
            (unsigned)__float_as_int(zr.y), (unsigned)__float_as_int(zr.y), false, false);
        lo = (f32x2){ __int_as_float((int)t0[0]), __int_as_float((int)t1[0]) };
        hi = (f32x2){ __int_as_float((int)t0[1]), __int_as_float((int)t1[1]) };
        ar = pk_fma(c.psgn[0], hi, lo);
        t0 = __builtin_amdgcn_permlane32_swap(
            (unsigned)__float_as_int(zi.x), (unsigned)__float_as_int(zi.x), false, false);
        t1 = __builtin_amdgcn_permlane32_swap(
            (unsigned)__float_as_int(zi.y), (unsigned)__float_as_int(zi.y), false, false);
        lo = (f32x2){ __int_as_float((int)t0[0]), __int_as_float((int)t1[0]) };
        hi = (f32x2){ __int_as_float((int)t0[1]), __int_as_float((int)t1[1]) };
        ai = pk_fma(c.psgn[0], hi, lo);
    }
    zr = pk_fma(ar, c.C[0], ai * c.Sn[0]);
    zi = pk_fma(ai, c.C[0], ar * c.S[0]);
    // ---- stage 1: xor16 via permlane16_swap ----
    {
        uint2v t0 = __builtin_amdgcn_permlane16_swap(
            (unsigned)__float_as_int(zr.x), (unsigned)__float_as_int(zr.x), false, false);
        uint2v t1 = __builtin_amdgcn_permlane16_swap(
            (unsigned)__float_as_int(zr.y), (unsigned)__float_as_int(zr.y), false, false);
        lo = (f32x2){ __int_as_float((int)t0[0]), __int_as_float((int)t1[0]) };
        hi = (f32x2){ __int_as_float((int)t0[1]), __int_as_float((int)t1[1]) };
        ar = pk_fma(c.psgn[1], hi, lo);
        t0 = __builtin_amdgcn_permlane16_swap(
            (unsigned)__float_as_int(zi.x), (unsigned)__float_as_int(zi.x), false, false);
        t1 = __builtin_amdgcn_permlane16_swap(
            (unsigned)__float_as_int(zi.y), (unsigned)__float_as_int(zi.y), false, false);
        lo = (f32x2){ __int_as_float((int)t0[0]), __int_as_float((int)t1[0]) };
        hi = (f32x2){ __int_as_float((int)t0[1]), __int_as_float((int)t1[1]) };
        ai = pk_fma(c.psgn[1], hi, lo);
    }
    zr = pk_fma(ar, c.C[1], ai * c.Sn[1]);
    zi = pk_fma(ai, c.C[1], ar * c.S[1]);
    // ---- stage 2: xor8 via DPP row_ror:8; bfly = sgn*mine + partner ----
    pr.x = dpp_mov<0x128>(zr.x); pr.y = dpp_mov<0x128>(zr.y);
    pi.x = dpp_mov<0x128>(zi.x); pi.y = dpp_mov<0x128>(zi.y);
    ar = pk_fma(c.psgn[2], zr, pr);
    ai = pk_fma(c.psgn[2], zi, pi);
    zr = pk_fma(ar, c.C[2], ai * c.Sn[2]);
    zi = pk_fma(ai, c.C[2], ar * c.S[2]);
    // ---- stage 3: xor4 via ds_swizzle ----
    pr.x = swz4(zr.x); pr.y = swz4(zr.y);
    pi.x = swz4(zi.x); pi.y = swz4(zi.y);
    ar = pk_fma(c.psgn[3], zr, pr);
    ai = pk_fma(c.psgn[3], zi, pi);
    zr = pk_fma(ar, c.C[3], ai * c.Sn[3]);
    zi = pk_fma(ai, c.C[3], ar * c.S[3]);
    // ---- stage 4: xor2 via DPP quad_perm [2,3,0,1]; twiddle is 1 or -i ----
    pr.x = dpp_mov<0x4E>(zr.x); pr.y = dpp_mov<0x4E>(zr.y);
    pi.x = dpp_mov<0x4E>(zi.x); pi.y = dpp_mov<0x4E>(zi.y);
    ar = pk_fma(c.psgn[4], zr, pr);
    ai = pk_fma(c.psgn[4], zi, pi);
    zr = c.rot4 ? ai : ar;          // (ar + i*ai) * (-i) = ai - i*ar
    zi = c.rot4 ? -ar : ai;
    // ---- stage 5: xor1 via DPP quad_perm [1,0,3,2]; twiddle == 1 ----
    pr.x = dpp_mov<0xB1>(zr.x); pr.y = dpp_mov<0xB1>(zr.y);
    pi.x = dpp_mov<0xB1>(zi.x); pi.y = dpp_mov<0xB1>(zi.y);
    zr = pk_fma(c.psgn[5], zr, pr);
    zi = pk_fma(c.psgn[5], zi, pi);
}

// packed epilogue for a row pair — proven R6/R8 form
template <bool STORE_PAIR>
__device__ __forceinline__ void epilogue_pair(f32x2 zr, f32x2 zi,
                                              float* __restrict__ out,
                                              int r0, const LaneConst& c) {
    f32x2 p0r = { rdlane(zr.x, 52), rdlane(zr.y, 52) };
    f32x2 p0i = { rdlane(zi.x, 52), rdlane(zi.y, 52) };
    f32x2 p1r = { rdlane(zr.x, 38), rdlane(zr.y, 38) };
    f32x2 p1i = { rdlane(zi.x, 38), rdlane(zi.y, 38) };
    f32x2 p2r = { rdlane(zr.x, 57), rdlane(zr.y, 57) };
    f32x2 p2i = { rdlane(zi.x, 57), rdlane(zi.y, 57) };
    f32x2 p3r = { rdlane(zr.x, 43), rdlane(zr.y, 43) };
    f32x2 p3i = { rdlane(zi.x, 43), rdlane(zi.y, 43) };
    f32x2 hr = c.pw0 * p0r;
    hr = pk_fma(c.pw1, p1r, hr);
    hr = pk_fma(c.pw2, p2r, hr);
    hr = pk_fma(c.pw3, p3r, hr);
    f32x2 hi = c.pw0 * p0i;
    hi = pk_fma(c.pw1, p1i, hi);
    hi = pk_fma(c.pw2, p2i, hi);
    hi = pk_fma(c.pw3, p3i, hi);
    f32x2 den = pk_fma(hr, hr, pk_fma(hi, hi, (f32x2){1e-8f, 1e-8f}));
    f32x2 rd;
    rd.x = __builtin_amdgcn_rcpf(den.x);
    rd.y = __builtin_amdgcn_rcpf(den.y);
    f32x2 numr = pk_fma(zr, hr, zi * hi);
    f32x2 numi = pk_fma(zi, hr, zr * (-hi));
    f32x2 eqr = numr * rd;
    f32x2 eqi = numi * rd;
    float* po0 = out + (size_t)r0 * 128;
    __builtin_nontemporal_store(eqr.x, po0 + c.kk);
    __builtin_nontemporal_store(eqi.x, po0 + 64 + c.kk);
    if (STORE_PAIR) {
        float* po1 = po0 + 128;
        __builtin_nontemporal_store(eqr.y, po1 + c.kk);
        __builtin_nontemporal_store(eqi.y, po1 + 64 + c.kk);
    }
}

__device__ __forceinline__ void do_rows8(const float* __restrict__ x,
                                         float* __restrict__ out,
                                         int r0, int lane, const LaneConst& c) {
    float xr[8], xi[8];
    #pragma unroll
    for (int j = 0; j < 8; ++j) {
        const float* px = x + (size_t)(r0 + j) * 128;
        xr[j] = px[lane];
        xi[j] = px[64 + lane];
    }
    #pragma unroll
    for (int p = 0; p < 4; ++p) {
        f32x2 zr = { xr[2 * p], xr[2 * p + 1] };
        f32x2 zi = { xi[2 * p], xi[2 * p + 1] };
        fft_pair(zr, zi, c);
        epilogue_pair<true>(zr, zi, out, r0 + 2 * p, c);
    }
}

__global__ __launch_bounds__(256) void ofdm_kernel(const float* __restrict__ x,
                                                   float* __restrict__ out,
                                                   int nrows) {
    const int lane = threadIdx.x & 63;
    const int wid  = threadIdx.x >> 6;
    const int wavesPerBlock = blockDim.x >> 6;
    const int gw = blockIdx.x * wavesPerBlock + wid;
    const int gstride = gridDim.x * wavesPerBlock;

    LaneConst c;
    #pragma unroll
    for (int s = 0; s < 6; ++s) {
        const int half = 32 >> s;
        const bool up = (lane & half) != 0;
        const float sg = up ? -1.0f : 1.0f;
        c.psgn[s] = (f32x2){sg, sg};
        if (s < 4) {
            const int t = (lane & (half - 1)) << s;
            // v_cos_f32 / v_sin_f32 take REVOLUTIONS: t*(pi/32) rad == t/64 rev
            const float fr = (float)t * 0.015625f;
            const float cc = up ? __builtin_amdgcn_cosf(fr) : 1.0f;
            const float ss = up ? -__builtin_amdgcn_sinf(fr) : 0.0f; // W = e^{-i th}
            c.C[s]  = (f32x2){cc, cc};
            c.S[s]  = (f32x2){ss, ss};
            c.Sn[s] = (f32x2){-ss, -ss};
        }
    }
    // stage 4: t = (lane&1)<<4 -> theta in {0, pi/2}; up lanes with t=16: *-i
    c.rot4 = ((lane & 2) != 0) && ((lane & 1) != 0);

    c.kk = (int)(__brev((unsigned)lane) >> 26);
    const int seg = (c.kk <= 25) ? 0 : (c.kk <= 39) ? 1 : 2; // pilots 11,25,39,53
    float a = (float)(c.kk - (11 + seg * 14)) * (1.0f / 14.0f);
    a = fminf(fmaxf(a, 0.0f), 1.0f);
    float w0 = 0, w1 = 0, w2 = 0, w3 = 0;
    const float wa = 1.0f - a, wb = a;
    if (seg == 0) { w0 = wa; w1 = wb; }
    else if (seg == 1) { w1 = wa; w2 = wb; }
    else { w2 = wa; w3 = wb; }
    c.pw0 = (f32x2){w0, w0}; c.pw1 = (f32x2){w1, w1};
    c.pw2 = (f32x2){w2, w2}; c.pw3 = (f32x2){w3, w3};

    const int step = gstride * 8;
    int r = gw * 8;
    for (; r + 8 <= nrows; r += step)
        do_rows8(x, out, r, lane, c);

    // tail (unused for nrows % 8 == 0): strided row pairs, then odd row
    const int tail = nrows & ~7;
    for (int rr = tail + gw * 2; rr + 2 <= nrows; rr += gstride * 2) {
        const float* p0 = x + (size_t)rr * 128;
        f32x2 zr = { p0[lane],      p0[128 + lane] };
        f32x2 zi = { p0[64 + lane], p0[192 + lane] };
        fft_pair(zr, zi, c);
        epilogue_pair<true>(zr, zi, out, rr, c);
    }
    if ((nrows & 1) && gw == 0) {
        const int rr = nrows - 1;
        const float* p0 = x + (size_t)rr * 128;
        f32x2 zr = { p0[lane], p0[lane] };
        f32x2 zi = { p0[64 + lane], p0[64 + lane] };
        fft_pair(zr, zi, c);
        epilogue_pair<false>(zr, zi, out, rr, c);
    }
}

extern "C" void kernel_launch(void* const* d_in, const int* in_sizes, int n_in,
                              void* d_out, int out_size, void* d_ws, size_t ws_size,
                              hipStream_t stream) {
    const float* x = (const float*)d_in[0];
    float* out = (float*)d_out;
    const int nrows = in_sizes[0] / 128;   // 262144
    const int block = 256;                 // 4 waves/block
    const int grid = 2048;                 // 8192 waves, 4 iters x 8 rows
    hipLaunchKernelGGL(ofdm_kernel, dim3(grid), dim3(block), 0, stream,
                       x, out, nrows);
}

// Round 11
// 45.902 us; speedup vs baseline: 1.0530x; 1.0112x over previous
//
#include <hip/hip_runtime.h>
#include <math.h>

// OFDM: per-row 64-pt complex FFT (radix-2 DIF, lane-per-bin), fully
// row-PAIR packed (v_pk_fma_f32 via compiler; no inline asm).
// Cross-lane per 32-bit reg: xor32 -> permlane32_swap, xor16 ->
// permlane16_swap, xor8 -> DPP row_ror:8, xor4 -> ds_swizzle,
// xor2/xor1 -> DPP quad_perm. Stage-4 twiddle = +/-i -> selects.
// Twiddle setup: v_cos_f32/v_sin_f32 in REVOLUTIONS (t/64).
// R10 experiment: PLAIN cached stores (NT stores forced a synchronous HBM
// write stream ~3-4 TB/s ceiling -> 45us wall; cached stores retire in
// L2/L3 and write back asynchronously).
// Epilogue packed, bit-reversed domain; scatter-store restores order.

typedef float f32x2 __attribute__((ext_vector_type(2)));
typedef unsigned int uint2v __attribute__((ext_vector_type(2)));

struct LaneConst {
    f32x2 psgn[6];            // stages 0..5 butterfly sign (broadcast pair)
    f32x2 C[4], S[4], Sn[4];  // stages 0..3 twiddle (S = -sin; stage4 = +/-i, stage5 = 1)
    bool  rot4;               // stage-4: this lane multiplies by -i
    f32x2 pw0, pw1, pw2, pw3; // pilot interp weights (broadcast pair)
    int   kk;                 // natural bin index = brev6(lane)
};

__device__ __forceinline__ f32x2 pk_fma(f32x2 a, f32x2 b, f32x2 cc) {
#if __has_builtin(__builtin_elementwise_fma)
    return __builtin_elementwise_fma(a, b, cc);
#else
    return a * b + cc;
#endif
}

template <int CTRL>
__device__ __forceinline__ float dpp_mov(float x) {
    return __int_as_float(__builtin_amdgcn_update_dpp(
        0, __float_as_int(x), CTRL, 0xF, 0xF, true));
}
__device__ __forceinline__ float swz4(float x) {
    return __int_as_float(__builtin_amdgcn_ds_swizzle(__float_as_int(x), 0x101F));
}
__device__ __forceinline__ float rdlane(float x, int l) {
    return __int_as_float(__builtin_amdgcn_readlane(__float_as_int(x), l));
}

// full packed FFT for a row pair (rows r0, r0+1 in .x/.y of zr, zi)
__device__ __forceinline__ void fft_pair(f32x2& zr, f32x2& zi, const LaneConst& c) {
    f32x2 lo, hi, ar, ai, pr, pi;
    // ---- stage 0: xor32 via permlane32_swap; bfly = sgn*hi + lo ----
    {
        uint2v t0 = __builtin_amdgcn_permlane32_swap(
            (unsigned)__float_as_int(zr.x), (unsigned)__float_as_int(zr.x), false, false);
        uint2v t1 = __builtin_amdgcn_permlane32_swap(
            (unsigned)__float_as_int(zr.y), (unsigned)__float_as_int(zr.y), false, false);
        lo = (f32x2){ __int_as_float((int)t0[0]), __int_as_float((int)t1[0]) };
        hi = (f32x2){ __int_as_float((int)t0[1]), __int_as_float((int)t1[1]) };
        ar = pk_fma(c.psgn[0], hi, lo);
        t0 = __builtin_amdgcn_permlane32_swap(
            (unsigned)__float_as_int(zi.x), (unsigned)__float_as_int(zi.x), false, false);
        t1 = __builtin_amdgcn_permlane32_swap(
            (unsigned)__float_as_int(zi.y), (unsigned)__float_as_int(zi.y), false, false);
        lo = (f32x2){ __int_as_float((int)t0[0]), __int_as_float((int)t1[0]) };
        hi = (f32x2){ __int_as_float((int)t0[1]), __int_as_float((int)t1[1]) };
        ai = pk_fma(c.psgn[0], hi, lo);
    }
    zr = pk_fma(ar, c.C[0], ai * c.Sn[0]);
    zi = pk_fma(ai, c.C[0], ar * c.S[0]);
    // ---- stage 1: xor16 via permlane16_swap ----
    {
        uint2v t0 = __builtin_amdgcn_permlane16_swap(
            (unsigned)__float_as_int(zr.x), (unsigned)__float_as_int(zr.x), false, false);
        uint2v t1 = __builtin_amdgcn_permlane16_swap(
            (unsigned)__float_as_int(zr.y), (unsigned)__float_as_int(zr.y), false, false);
        lo = (f32x2){ __int_as_float((int)t0[0]), __int_as_float((int)t1[0]) };
        hi = (f32x2){ __int_as_float((int)t0[1]), __int_as_float((int)t1[1]) };
        ar = pk_fma(c.psgn[1], hi, lo);
        t0 = __builtin_amdgcn_permlane16_swap(
            (unsigned)__float_as_int(zi.x), (unsigned)__float_as_int(zi.x), false, false);
        t1 = __builtin_amdgcn_permlane16_swap(
            (unsigned)__float_as_int(zi.y), (unsigned)__float_as_int(zi.y), false, false);
        lo = (f32x2){ __int_as_float((int)t0[0]), __int_as_float((int)t1[0]) };
        hi = (f32x2){ __int_as_float((int)t0[1]), __int_as_float((int)t1[1]) };
        ai = pk_fma(c.psgn[1], hi, lo);
    }
    zr = pk_fma(ar, c.C[1], ai * c.Sn[1]);
    zi = pk_fma(ai, c.C[1], ar * c.S[1]);
    // ---- stage 2: xor8 via DPP row_ror:8; bfly = sgn*mine + partner ----
    pr.x = dpp_mov<0x128>(zr.x); pr.y = dpp_mov<0x128>(zr.y);
    pi.x = dpp_mov<0x128>(zi.x); pi.y = dpp_mov<0x128>(zi.y);
    ar = pk_fma(c.psgn[2], zr, pr);
    ai = pk_fma(c.psgn[2], zi, pi);
    zr = pk_fma(ar, c.C[2], ai * c.Sn[2]);
    zi = pk_fma(ai, c.C[2], ar * c.S[2]);
    // ---- stage 3: xor4 via ds_swizzle ----
    pr.x = swz4(zr.x); pr.y = swz4(zr.y);
    pi.x = swz4(zi.x); pi.y = swz4(zi.y);
    ar = pk_fma(c.psgn[3], zr, pr);
    ai = pk_fma(c.psgn[3], zi, pi);
    zr = pk_fma(ar, c.C[3], ai * c.Sn[3]);
    zi = pk_fma(ai, c.C[3], ar * c.S[3]);
    // ---- stage 4: xor2 via DPP quad_perm [2,3,0,1]; twiddle is 1 or -i ----
    pr.x = dpp_mov<0x4E>(zr.x); pr.y = dpp_mov<0x4E>(zr.y);
    pi.x = dpp_mov<0x4E>(zi.x); pi.y = dpp_mov<0x4E>(zi.y);
    ar = pk_fma(c.psgn[4], zr, pr);
    ai = pk_fma(c.psgn[4], zi, pi);
    zr = c.rot4 ? ai : ar;          // (ar + i*ai) * (-i) = ai - i*ar
    zi = c.rot4 ? -ar : ai;
    // ---- stage 5: xor1 via DPP quad_perm [1,0,3,2]; twiddle == 1 ----
    pr.x = dpp_mov<0xB1>(zr.x); pr.y = dpp_mov<0xB1>(zr.y);
    pi.x = dpp_mov<0xB1>(zi.x); pi.y = dpp_mov<0xB1>(zi.y);
    zr = pk_fma(c.psgn[5], zr, pr);
    zi = pk_fma(c.psgn[5], zi, pi);
}

// packed epilogue for a row pair — R6/R8 form, plain cached stores
template <bool STORE_PAIR>
__device__ __forceinline__ void epilogue_pair(f32x2 zr, f32x2 zi,
                                              float* __restrict__ out,
                                              int r0, const LaneConst& c) {
    f32x2 p0r = { rdlane(zr.x, 52), rdlane(zr.y, 52) };
    f32x2 p0i = { rdlane(zi.x, 52), rdlane(zi.y, 52) };
    f32x2 p1r = { rdlane(zr.x, 38), rdlane(zr.y, 38) };
    f32x2 p1i = { rdlane(zi.x, 38), rdlane(zi.y, 38) };
    f32x2 p2r = { rdlane(zr.x, 57), rdlane(zr.y, 57) };
    f32x2 p2i = { rdlane(zi.x, 57), rdlane(zi.y, 57) };
    f32x2 p3r = { rdlane(zr.x, 43), rdlane(zr.y, 43) };
    f32x2 p3i = { rdlane(zi.x, 43), rdlane(zi.y, 43) };
    f32x2 hr = c.pw0 * p0r;
    hr = pk_fma(c.pw1, p1r, hr);
    hr = pk_fma(c.pw2, p2r, hr);
    hr = pk_fma(c.pw3, p3r, hr);
    f32x2 hi = c.pw0 * p0i;
    hi = pk_fma(c.pw1, p1i, hi);
    hi = pk_fma(c.pw2, p2i, hi);
    hi = pk_fma(c.pw3, p3i, hi);
    f32x2 den = pk_fma(hr, hr, pk_fma(hi, hi, (f32x2){1e-8f, 1e-8f}));
    f32x2 rd;
    rd.x = __builtin_amdgcn_rcpf(den.x);
    rd.y = __builtin_amdgcn_rcpf(den.y);
    f32x2 numr = pk_fma(zr, hr, zi * hi);
    f32x2 numi = pk_fma(zi, hr, zr * (-hi));
    f32x2 eqr = numr * rd;
    f32x2 eqi = numi * rd;
    float* po0 = out + (size_t)r0 * 128;
    po0[c.kk]      = eqr.x;
    po0[64 + c.kk] = eqi.x;
    if (STORE_PAIR) {
        float* po1 = po0 + 128;
        po1[c.kk]      = eqr.y;
        po1[64 + c.kk] = eqi.y;
    }
}

__device__ __forceinline__ void do_rows8(const float* __restrict__ x,
                                         float* __restrict__ out,
                                         int r0, int lane, const LaneConst& c) {
    float xr[8], xi[8];
    #pragma unroll
    for (int j = 0; j < 8; ++j) {
        const float* px = x + (size_t)(r0 + j) * 128;
        xr[j] = px[lane];
        xi[j] = px[64 + lane];
    }
    #pragma unroll
    for (int p = 0; p < 4; ++p) {
        f32x2 zr = { xr[2 * p], xr[2 * p + 1] };
        f32x2 zi = { xi[2 * p], xi[2 * p + 1] };
        fft_pair(zr, zi, c);
        epilogue_pair<true>(zr, zi, out, r0 + 2 * p, c);
    }
}

__global__ __launch_bounds__(256) void ofdm_kernel(const float* __restrict__ x,
                                                   float* __restrict__ out,
                                                   int nrows) {
    const int lane = threadIdx.x & 63;
    const int wid  = threadIdx.x >> 6;
    const int wavesPerBlock = blockDim.x >> 6;
    const int gw = blockIdx.x * wavesPerBlock + wid;
    const int gstride = gridDim.x * wavesPerBlock;

    LaneConst c;
    #pragma unroll
    for (int s = 0; s < 6; ++s) {
        const int half = 32 >> s;
        const bool up = (lane & half) != 0;
        const float sg = up ? -1.0f : 1.0f;
        c.psgn[s] = (f32x2){sg, sg};
        if (s < 4) {
            const int t = (lane & (half - 1)) << s;
            // v_cos_f32 / v_sin_f32 take REVOLUTIONS: t*(pi/32) rad == t/64 rev
            const float fr = (float)t * 0.015625f;
            const float cc = up ? __builtin_amdgcn_cosf(fr) : 1.0f;
            const float ss = up ? -__builtin_amdgcn_sinf(fr) : 0.0f; // W = e^{-i th}
            c.C[s]  = (f32x2){cc, cc};
            c.S[s]  = (f32x2){ss, ss};
            c.Sn[s] = (f32x2){-ss, -ss};
        }
    }
    // stage 4: t = (lane&1)<<4 -> theta in {0, pi/2}; up lanes with t=16: *-i
    c.rot4 = ((lane & 2) != 0) && ((lane & 1) != 0);

    c.kk = (int)(__brev((unsigned)lane) >> 26);
    const int seg = (c.kk <= 25) ? 0 : (c.kk <= 39) ? 1 : 2; // pilots 11,25,39,53
    float a = (float)(c.kk - (11 + seg * 14)) * (1.0f / 14.0f);
    a = fminf(fmaxf(a, 0.0f), 1.0f);
    float w0 = 0, w1 = 0, w2 = 0, w3 = 0;
    const float wa = 1.0f - a, wb = a;
    if (seg == 0) { w0 = wa; w1 = wb; }
    else if (seg == 1) { w1 = wa; w2 = wb; }
    else { w2 = wa; w3 = wb; }
    c.pw0 = (f32x2){w0, w0}; c.pw1 = (f32x2){w1, w1};
    c.pw2 = (f32x2){w2, w2}; c.pw3 = (f32x2){w3, w3};

    const int step = gstride * 8;
    int r = gw * 8;
    for (; r + 8 <= nrows; r += step)
        do_rows8(x, out, r, lane, c);

    // tail (unused for nrows % 8 == 0): strided row pairs, then odd row
    const int tail = nrows & ~7;
    for (int rr = tail + gw * 2; rr + 2 <= nrows; rr += gstride * 2) {
        const float* p0 = x + (size_t)rr * 128;
        f32x2 zr = { p0[lane],      p0[128 + lane] };
        f32x2 zi = { p0[64 + lane], p0[192 + lane] };
        fft_pair(zr, zi, c);
        epilogue_pair<true>(zr, zi, out, rr, c);
    }
    if ((nrows & 1) && gw == 0) {
        const int rr = nrows - 1;
        const float* p0 = x + (size_t)rr * 128;
        f32x2 zr = { p0[lane], p0[lane] };
        f32x2 zi = { p0[64 + lane], p0[64 + lane] };
        fft_pair(zr, zi, c);
        epilogue_pair<false>(zr, zi, out, rr, c);
    }
}

extern "C" void kernel_launch(void* const* d_in, const int* in_sizes, int n_in,
                              void* d_out, int out_size, void* d_ws, size_t ws_size,
                              hipStream_t stream) {
    const float* x = (const float*)d_in[0];
    float* out = (float*)d_out;
    const int nrows = in_sizes[0] / 128;   // 262144
    const int block = 256;                 // 4 waves/block
    const int grid = 2048;                 // 8192 waves, 4 iters x 8 rows
    hipLaunchKernelGGL(ofdm_kernel, dim3(grid), dim3(block), 0, stream,
                       x, out, nrows);
}